// Round 5
// baseline (409.366 us; speedup 1.0000x reference)
//
#include <hip/hip_runtime.h>
#include <hip/hip_bf16.h>
#include <math.h>

#define Vv   32
#define Dd   128
#define Hh   8
#define Bb   8
#define Mm   2048
#define BM   (Bb*Mm)        // 16384
#define NEL  (BM*Dd)        // 2097152
#define XNS  140            // LDS stride (halves) for 128-col tiles, bank-padded
#define QKS  396            // LDS stride (halves) for 384-col qkv tile, bank-padded
#define NBLK 256            // 1 block/CU: co-residency guaranteed with 2x margin

typedef _Float16 half4_t __attribute__((ext_vector_type(4)));
typedef _Float16 half8_t __attribute__((ext_vector_type(8)));
typedef __fp16   fp16x2  __attribute__((ext_vector_type(2)));
typedef float    float4_t __attribute__((ext_vector_type(4)));
#define MFMA16 __builtin_amdgcn_mfma_f32_16x16x16f16
#define MFMA32 __builtin_amdgcn_mfma_f32_16x16x32_f16

#if __has_builtin(__builtin_amdgcn_exp2f)
__device__ __forceinline__ float fexp2(float x) { return __builtin_amdgcn_exp2f(x); }
#else
__device__ __forceinline__ float fexp2(float x) { return __expf(x * 0.6931471805599453f); }
#endif

// ---------------- hand-rolled grid barrier (device-scope atomics + agent fences) ----------------
// 256 blocks at 1 block/CU (capacity 2/CU at 128 VGPR) -> co-residency has 2x margin.
__device__ __forceinline__ void grid_bar(unsigned* cnt, unsigned* gen) {
    __syncthreads();                       // block stores drained (vmcnt0 at s_barrier)
    if (threadIdx.x == 0) {
        __threadfence();                   // release: write back this XCD's L2
        unsigned g = __hip_atomic_load(gen, __ATOMIC_RELAXED, __HIP_MEMORY_SCOPE_AGENT);
        unsigned a = __hip_atomic_fetch_add(cnt, 1u, __ATOMIC_ACQ_REL, __HIP_MEMORY_SCOPE_AGENT) + 1u;
        if (a == (unsigned)NBLK) {
            __hip_atomic_store(cnt, 0u, __ATOMIC_RELAXED, __HIP_MEMORY_SCOPE_AGENT);
            __hip_atomic_fetch_add(gen, 1u, __ATOMIC_RELEASE, __HIP_MEMORY_SCOPE_AGENT);
        } else {
            int spins = 0;
            while (__hip_atomic_load(gen, __ATOMIC_ACQUIRE, __HIP_MEMORY_SCOPE_AGENT) == g) {
                __builtin_amdgcn_s_sleep(2);
                if (++spins > (1 << 19)) break;   // ~30ms failsafe: fail fast, never hang
            }
        }
        __threadfence();                   // acquire: invalidate L1/L2 before reads
    }
    __syncthreads();
}

__global__ __launch_bounds__(64) void init_kernel(unsigned* __restrict__ bar) {
    bar[threadIdx.x] = 0u;                 // zero cnt + gen lines (poisoned between iters)
}

// ---------------- attention helpers (plain-add denominator) ----------------
__device__ __forceinline__ half4_t attn_exps(float4_t st, float& ls) {
    float p0 = fexp2(st[0]), p1 = fexp2(st[1]);
    float p2 = fexp2(st[2]), p3 = fexp2(st[3]);
    ls += (p0 + p1) + (p2 + p3);
    fp16x2 lo = __builtin_amdgcn_cvt_pkrtz(p0, p1);
    fp16x2 hi = __builtin_amdgcn_cvt_pkrtz(p2, p3);
    half4_t pf;
    pf[0] = (_Float16)lo[0]; pf[1] = (_Float16)lo[1];
    pf[2] = (_Float16)hi[0]; pf[3] = (_Float16)hi[1];
    return pf;
}
__device__ __forceinline__ half4_t attn_exps_masked(float4_t st, float& ls, int r, int c) {
    float p0 = (4 * c + 0 <= r) ? fexp2(st[0]) : 0.f;
    float p1 = (4 * c + 1 <= r) ? fexp2(st[1]) : 0.f;
    float p2 = (4 * c + 2 <= r) ? fexp2(st[2]) : 0.f;
    float p3 = (4 * c + 3 <= r) ? fexp2(st[3]) : 0.f;
    ls += (p0 + p1) + (p2 + p3);
    fp16x2 lo = __builtin_amdgcn_cvt_pkrtz(p0, p1);
    fp16x2 hi = __builtin_amdgcn_cvt_pkrtz(p2, p3);
    half4_t pf;
    pf[0] = (_Float16)lo[0]; pf[1] = (_Float16)lo[1];
    pf[2] = (_Float16)hi[0]; pf[3] = (_Float16)hi[1];
    return pf;
}

// =====================================================================================
// ONE plain kernel, 256 blocks x 512 threads (1 block/CU), hand-rolled grid barriers.
// Each phase does 2x the per-block work of the verified R2 kernels.
// =====================================================================================
__global__ __launch_bounds__(512, 4) void mega_kernel(
    const int*   __restrict__ idx,
    const int*   __restrict__ targets,
    const float* __restrict__ emb,
    const float* __restrict__ scale,
    const float* __restrict__ Wq,
    const float* __restrict__ Wk,
    const float* __restrict__ Wv,
    const float* __restrict__ in_w,
    const float* __restrict__ in_b,
    const float* __restrict__ out_pw,
    const float* __restrict__ out_pb,
    const float* __restrict__ lin_w,
    const float* __restrict__ lin_b,
    const float* __restrict__ out_w,
    const float* __restrict__ out_b,
    char* __restrict__ ws,
    float* __restrict__ out)
{
    const size_t MB = 1024 * 1024;
    _Float16* xh16  = (_Float16*)ws;                 // gathered x (f16)
    _Float16* xnh   = (_Float16*)(ws + 4 * MB);      // normed x (resid for D)
    _Float16* Oh    = (_Float16*)(ws + 8 * MB);      // attn out
    _Float16* xresh = (_Float16*)(ws + 12 * MB);     // residual-2
    _Float16* ffoh  = (_Float16*)(ws + 16 * MB);     // ffn out
    _Float16* Qp    = (_Float16*)(ws + 20 * MB);
    _Float16* Kp    = (_Float16*)(ws + 24 * MB);
    _Float16* Vp    = (_Float16*)(ws + 28 * MB);
    float*    cosT  = (float*)(ws + 32 * MB);
    float*    sinT  = cosT + Mm * 64;
    float*    part1 = sinT + Mm * 64;                // 1024 used
    float*    part2 = part1 + 2048;                  // 512 used
    _Float16* Wh    = (_Float16*)(part2 + 512);      // 135168 halves
    unsigned* cnt   = (unsigned*)(ws + 40 * MB);     // barrier count
    unsigned* gen   = (unsigned*)(ws + 40 * MB) + 32;// barrier generation (separate line)
    float*    nllPart = (float*)(ws + 40 * MB + 4096);
    float*    lossOut = out + (size_t)BM * Vv;
    float*    logits  = out;

    __shared__ union SH {
        struct { _Float16 xn[32 * XNS]; _Float16 qkv[32 * QKS]; float wsum[8]; } b;
        struct { float mrg[4][10][64]; } c;
        struct { _Float16 At[128 * XNS]; float wn[8]; } f;
        struct { float wsum[8]; } a;
    } sh;

    int tid  = threadIdx.x;
    int bid  = blockIdx.x;
    int wave = tid >> 6, lane = tid & 63;
    int r = lane & 15, c = lane >> 4;
    int aoff = c * 8;                    // A-frag: contiguous 8 halves (k = c*8+j)
    int boff = r * 16 + (c & 1) * 8;     // B-frag within 16x16 tile
    int bsel = c >> 1;

    // ================= PHASE A: weights->f16 blocked, RoPE tables, gather + ssq =================
    #pragma unroll 1
    for (int sweep = 0; sweep < 3; sweep++) {
        int gid = sweep * 131072 + bid * 512 + tid;
        if (gid < 135168) {
            const float* src;
            int i;
            if (gid < 131072) {
                int seg = gid >> 14; i = gid & 16383;
                src = seg == 0 ? Wq : seg == 1 ? Wk : seg == 2 ? Wv :
                      seg < 6 ? in_w + (size_t)(seg - 3) * 16384 :
                      seg == 6 ? out_pw : lin_w;
            } else { src = out_w; i = gid - 131072; }
            int tile = i >> 8, within = i & 255;
            int nt = tile >> 3, kk = tile & 7;
            int rr = within >> 4, cc = within & 15;
            Wh[gid] = (_Float16)src[(nt * 16 + rr) * 128 + kk * 16 + cc];
        } else if (gid < 266240) {
            int rid = gid - 135168;                  // Mm*64
            int i = rid & 63, m = rid >> 6;
            float ex = -2.0f * ((float)i - 1.0f) / 128.0f;
            float basef = expf(ex * 9.210340371976184f);
            float ang = (float)m * basef;
            cosT[rid] = cosf(ang);
            sinT[rid] = sinf(ang);
        }
    }
    #pragma unroll 1
    for (int pass = 0; pass < 4; pass++) {
        int chunk = pass * 256 + bid;                // 1024 chunks of 16 tokens
        int slot = chunk * 512 + tid;
        int token = slot >> 5, t4 = slot & 31;
        float4 x = *(const float4*)(emb + (size_t)idx[token] * 128 + t4 * 4);
        half4_t o;
        o[0] = (_Float16)x.x; o[1] = (_Float16)x.y; o[2] = (_Float16)x.z; o[3] = (_Float16)x.w;
        *(half4_t*)(xh16 + (size_t)slot * 4) = o;
        float v = x.x * x.x + x.y * x.y + x.z * x.z + x.w * x.w;
        #pragma unroll
        for (int off = 32; off; off >>= 1) v += __shfl_xor(v, off);
        __syncthreads();
        if (lane == 0) sh.a.wsum[wave] = v;
        __syncthreads();
        if (tid == 0)
            part1[chunk] = ((sh.a.wsum[0] + sh.a.wsum[1]) + (sh.a.wsum[2] + sh.a.wsum[3])) +
                           ((sh.a.wsum[4] + sh.a.wsum[5]) + (sh.a.wsum[6] + sh.a.wsum[7]));
    }
    grid_bar(cnt, gen);

    // ================= PHASE B: rmsnorm + QKV + RoPE + in_proj (2 row-groups/block) =================
    #pragma unroll 1
    for (int it = 0; it < 2; it++) {
        int row0 = (bid + it * 256) * 32;
        __syncthreads();                             // LDS reuse guard between iterations
        {
            float v = (tid < 128) ? part1[(row0 >> 11) * 128 + tid] : 0.f;
            #pragma unroll
            for (int off = 32; off; off >>= 1) v += __shfl_xor(v, off);
            if ((tid & 63) == 0) sh.b.wsum[tid >> 6] = v;
        }
        __syncthreads();
        float iv = 512.0f / sqrtf(((sh.b.wsum[0] + sh.b.wsum[1]) + (sh.b.wsum[2] + sh.b.wsum[3])) +
                                  ((sh.b.wsum[4] + sh.b.wsum[5]) + (sh.b.wsum[6] + sh.b.wsum[7])));
        {
            int rw = tid >> 4, c8 = (tid & 15) * 8;
            int m = (row0 + rw) & (Mm - 1);
            half8_t x8 = *(const half8_t*)(xh16 + (size_t)(row0 + rw) * 128 + c8);
            const float* sp = scale + (size_t)m * 128 + c8;
            float4 s0 = *(const float4*)sp;
            float4 s1 = *(const float4*)(sp + 4);
            half8_t o8;
            o8[0] = (_Float16)((float)x8[0] * iv * s0.x);
            o8[1] = (_Float16)((float)x8[1] * iv * s0.y);
            o8[2] = (_Float16)((float)x8[2] * iv * s0.z);
            o8[3] = (_Float16)((float)x8[3] * iv * s0.w);
            o8[4] = (_Float16)((float)x8[4] * iv * s1.x);
            o8[5] = (_Float16)((float)x8[5] * iv * s1.y);
            o8[6] = (_Float16)((float)x8[6] * iv * s1.z);
            o8[7] = (_Float16)((float)x8[7] * iv * s1.w);
            *(half8_t*)(sh.b.xn + rw * XNS + c8) = o8;
            *(half8_t*)(xnh + (size_t)(row0 + rw) * 128 + c8) = o8;
        }
        __syncthreads();
        int nb = wave * 48;
        {
            float4_t acc[2][3];
            #pragma unroll
            for (int rt = 0; rt < 2; rt++)
                #pragma unroll
                for (int t = 0; t < 3; t++) acc[rt][t] = (float4_t){0.f, 0.f, 0.f, 0.f};
            #pragma unroll
            for (int kk = 0; kk < 4; kk++) {
                half8_t a0 = *(const half8_t*)(sh.b.xn + r * XNS + kk * 32 + aoff);
                half8_t a1 = *(const half8_t*)(sh.b.xn + (16 + r) * XNS + kk * 32 + aoff);
                half8_t wf[3];
                #pragma unroll
                for (int t = 0; t < 3; t++)
                    wf[t] = *(const half8_t*)(Wh + ((wave * 3 + t) * 8 + kk * 2 + bsel) * 256 + boff);
                #pragma unroll
                for (int t = 0; t < 3; t++) {
                    acc[0][t] = MFMA32(a0, wf[t], acc[0][t], 0, 0, 0);
                    acc[1][t] = MFMA32(a1, wf[t], acc[1][t], 0, 0, 0);
                }
            }
            #pragma unroll
            for (int rt = 0; rt < 2; rt++) {
                #pragma unroll
                for (int t = 0; t < 3; t++) {
                    int n = nb + t * 16 + r;
                    int ci = (n & 127) >> 1;
                    #pragma unroll
                    for (int reg = 0; reg < 4; reg++) {
                        int m2 = (row0 + rt * 16 + 4 * c + reg) & (Mm - 1);
                        float v = acc[rt][t][reg];
                        float vp = __shfl_xor(v, 1);
                        float cs = cosT[m2 * 64 + ci], sn = sinT[m2 * 64 + ci];
                        v = (n & 1) ? (-vp * sn + v * cs) : (v * cs + vp * sn);
                        sh.b.qkv[(rt * 16 + 4 * c + reg) * QKS + n] = (_Float16)v;
                    }
                }
            }
        }
        __syncthreads();
        {
            const _Float16* Whin = Wh + 3 * 16384;
            int seg_lo = nb >> 7;
            int seg_hi = (nb + 32) >> 7;
            float4_t acc[2][3];
            #pragma unroll
            for (int rt = 0; rt < 2; rt++)
                #pragma unroll
                for (int t = 0; t < 3; t++) acc[rt][t] = (float4_t){0.f, 0.f, 0.f, 0.f};
            #pragma unroll
            for (int kk = 0; kk < 4; kk++) {
                half8_t al0 = *(const half8_t*)(sh.b.qkv + r * QKS + seg_lo * 128 + kk * 32 + aoff);
                half8_t al1 = *(const half8_t*)(sh.b.qkv + (16 + r) * QKS + seg_lo * 128 + kk * 32 + aoff);
                half8_t ah0 = *(const half8_t*)(sh.b.qkv + r * QKS + seg_hi * 128 + kk * 32 + aoff);
                half8_t ah1 = *(const half8_t*)(sh.b.qkv + (16 + r) * QKS + seg_hi * 128 + kk * 32 + aoff);
                #pragma unroll
                for (int t = 0; t < 3; t++) {
                    int colg = nb + t * 16;
                    int seg = colg >> 7;
                    int ntl = (colg & 127) >> 4;
                    half8_t wf = *(const half8_t*)(Whin + ((seg * 8 + ntl) * 8 + kk * 2 + bsel) * 256 + boff);
                    bool lo = (seg == seg_lo);
                    acc[0][t] = MFMA32(lo ? al0 : ah0, wf, acc[0][t], 0, 0, 0);
                    acc[1][t] = MFMA32(lo ? al1 : ah1, wf, acc[1][t], 0, 0, 0);
                }
            }
            int bb = row0 >> 11;
            #pragma unroll
            for (int rt = 0; rt < 2; rt++) {
                int t16 = ((row0 + rt * 16) & 2047) >> 4;
                #pragma unroll
                for (int t = 0; t < 3; t++) {
                    int colg = nb + t * 16;
                    int seg = colg >> 7;
                    int h = (colg & 127) >> 4;
                    size_t tb = ((size_t)(bb * 8 + h) * 128 + t16) * 256;
                    float bv = in_b[colg + r];
                    _Float16* dst = seg == 0 ? Qp : seg == 1 ? Kp : Vp;
                    #pragma unroll
                    for (int reg = 0; reg < 4; reg++) {
                        float v = acc[rt][t][reg] + bv;
                        int key = 4 * c + reg;
                        if (seg < 2) dst[tb + key * 16 + r] = (_Float16)v;   // [token][d=r]
                        else         dst[tb + r * 16 + key] = (_Float16)v;   // [d=r][token]
                    }
                }
            }
        }
    }
    grid_bar(cnt, gen);

    // ================= PHASE C: flash attention (4 pairs/block x 4 passes) =================
    {
        int lofs = r * 16 + 4 * c;
        const _Float16 qscale = (_Float16)0.36067376f;   // 0.25 * log2(e)
        #pragma unroll 1
        for (int pass = 0; pass < 4; pass++) {
            int pair = pass * 1024 + bid * 4 + (wave >> 1);
            int split = wave & 1;
            int qa = pair & 63, bh = pair >> 6, qb = 127 - qa;
            const _Float16* Kb = Kp + (size_t)bh * 32768 + lofs;
            const _Float16* Vb = Vp + (size_t)bh * 32768 + lofs;
            const _Float16* Qb = Qp + (size_t)bh * 32768 + lofs;
            half4_t qfa = *(const half4_t*)(Qb + qa * 256);
            half4_t qfb = *(const half4_t*)(Qb + qb * 256);
            qfa *= qscale;
            qfb *= qscale;
            float4_t zero = {0.f, 0.f, 0.f, 0.f};
            float4_t oa = zero, ob = zero;
            float lsa = 0.f, lsb = 0.f;

            for (int kt = split; kt < qa; kt += 2) {
                half4_t k0 = *(const half4_t*)(Kb + (size_t)kt * 256);
                half4_t v0 = *(const half4_t*)(Vb + (size_t)kt * 256);
                float4_t sa = MFMA16(k0, qfa, zero, 0, 0, 0);
                float4_t sb = MFMA16(k0, qfb, zero, 0, 0, 0);
                half4_t pa = attn_exps(sa, lsa);
                half4_t pb = attn_exps(sb, lsb);
                oa = MFMA16(pa, v0, oa, 0, 0, 0);
                ob = MFMA16(pb, v0, ob, 0, 0, 0);
            }
            if ((qa & 1) == split) {
                half4_t k0 = *(const half4_t*)(Kb + (size_t)qa * 256);
                half4_t v0 = *(const half4_t*)(Vb + (size_t)qa * 256);
                float4_t sa = MFMA16(k0, qfa, zero, 0, 0, 0);
                float4_t sb = MFMA16(k0, qfb, zero, 0, 0, 0);
                half4_t pa = attn_exps_masked(sa, lsa, r, c);
                half4_t pb = attn_exps(sb, lsb);
                oa = MFMA16(pa, v0, oa, 0, 0, 0);
                ob = MFMA16(pb, v0, ob, 0, 0, 0);
            }
            {
                int s = qa + 1;
                if ((s & 1) != split) s++;
                for (int kt = s; kt < qb; kt += 2) {
                    half4_t k0 = *(const half4_t*)(Kb + (size_t)kt * 256);
                    half4_t v0 = *(const half4_t*)(Vb + (size_t)kt * 256);
                    float4_t sb = MFMA16(k0, qfb, zero, 0, 0, 0);
                    half4_t pb = attn_exps(sb, lsb);
                    ob = MFMA16(pb, v0, ob, 0, 0, 0);
                }
            }
            if ((qb & 1) == split) {
                half4_t k0 = *(const half4_t*)(Kb + (size_t)qb * 256);
                half4_t v0 = *(const half4_t*)(Vb + (size_t)qb * 256);
                float4_t sb = MFMA16(k0, qfb, zero, 0, 0, 0);
                half4_t pb = attn_exps_masked(sb, lsb, r, c);
                ob = MFMA16(pb, v0, ob, 0, 0, 0);
            }
            int pib = wave >> 1;
            __syncthreads();
            if (split == 1) {
                #pragma unroll
                for (int i = 0; i < 4; i++) {
                    sh.c.mrg[pib][i][lane] = oa[i];
                    sh.c.mrg[pib][4 + i][lane] = ob[i];
                }
                sh.c.mrg[pib][8][lane] = lsa;
                sh.c.mrg[pib][9][lane] = lsb;
            }
            __syncthreads();
            if (split == 0) {
                #pragma unroll
                for (int i = 0; i < 4; i++) {
                    oa[i] += sh.c.mrg[pib][i][lane];
                    ob[i] += sh.c.mrg[pib][4 + i][lane];
                }
                lsa += sh.c.mrg[pib][8][lane];
                lsb += sh.c.mrg[pib][9][lane];
                lsa += __shfl_xor(lsa, 16); lsa += __shfl_xor(lsa, 32);
                lsb += __shfl_xor(lsb, 16); lsb += __shfl_xor(lsb, 32);
                int b = bh >> 3, h = bh & 7;
                #pragma unroll
                for (int reg = 0; reg < 4; reg++) {
                    float la = __shfl(lsa, 4 * c + reg);
                    float lb = __shfl(lsb, 4 * c + reg);
                    Oh[(size_t)(b * Mm + qa * 16 + 4 * c + reg) * 128 + h * 16 + r] = (_Float16)(oa[reg] / la);
                    Oh[(size_t)(b * Mm + qb * 16 + 4 * c + reg) * 128 + h * 16 + r] = (_Float16)(ob[reg] / lb);
                }
            }
        }
    }
    grid_bar(cnt, gen);

    // ================= PHASE D: out_proj + residual -> xresh, ssq partials =================
    #pragma unroll 1
    for (int it = 0; it < 2; it++) {
        int rg = bid + it * 256;
        int row0 = rg * 32;
        __syncthreads();                             // LDS reuse guard
        const _Float16* W6 = Wh + 6 * 16384;
        {
            int rw = tid >> 4, c8 = (tid & 15) * 8;
            *(half8_t*)(sh.f.At + rw * XNS + c8) = *(const half8_t*)(Oh + (size_t)(row0 + rw) * 128 + c8);
        }
        __syncthreads();
        int n0 = wave * 16;
        float4_t acc[2];
        acc[0] = (float4_t){0.f, 0.f, 0.f, 0.f};
        acc[1] = (float4_t){0.f, 0.f, 0.f, 0.f};
        #pragma unroll
        for (int kk = 0; kk < 4; kk++) {
            half8_t a0 = *(const half8_t*)(sh.f.At + r * XNS + kk * 32 + aoff);
            half8_t a1 = *(const half8_t*)(sh.f.At + (16 + r) * XNS + kk * 32 + aoff);
            half8_t wf = *(const half8_t*)(W6 + (wave * 8 + kk * 2 + bsel) * 256 + boff);
            acc[0] = MFMA32(a0, wf, acc[0], 0, 0, 0);
            acc[1] = MFMA32(a1, wf, acc[1], 0, 0, 0);
        }
        float lssq = 0.f;
        int n = n0 + r;
        float bv = out_pb[n];
        #pragma unroll
        for (int rt = 0; rt < 2; rt++) {
            #pragma unroll
            for (int reg = 0; reg < 4; reg++) {
                int row = row0 + rt * 16 + 4 * c + reg;
                float v = acc[rt][reg] + bv + (float)xnh[(size_t)row * 128 + n];
                lssq += v * v;
                xresh[(size_t)row * 128 + n] = (_Float16)v;
            }
        }
        #pragma unroll
        for (int off = 32; off; off >>= 1) lssq += __shfl_xor(lssq, off);
        if (lane == 0) sh.f.wn[wave] = lssq;
        __syncthreads();
        if (tid == 0) part2[rg] = ((sh.f.wn[0] + sh.f.wn[1]) + (sh.f.wn[2] + sh.f.wn[3])) +
                                  ((sh.f.wn[4] + sh.f.wn[5]) + (sh.f.wn[6] + sh.f.wn[7]));
    }
    grid_bar(cnt, gen);

    // ================= PHASE E: rmsnorm + FFN + relu + residual -> ffoh =================
    #pragma unroll 1
    for (int it = 0; it < 2; it++) {
        int row0 = (bid + it * 256) * 32;
        const _Float16* W7 = Wh + 7 * 16384;
        float pv = part2[(row0 >> 11) * 64 + (tid & 63)];
        #pragma unroll
        for (int off = 32; off; off >>= 1) pv += __shfl_xor(pv, off);
        float iv = 512.0f / sqrtf(pv);
        __syncthreads();                             // LDS reuse guard
        {
            int rw = tid >> 4, c8 = (tid & 15) * 8;
            int m = (row0 + rw) & (Mm - 1);
            half8_t x8 = *(const half8_t*)(xresh + (size_t)(row0 + rw) * 128 + c8);
            const float* sp = scale + (size_t)m * 128 + c8;
            float4 s0 = *(const float4*)sp;
            float4 s1 = *(const float4*)(sp + 4);
            half8_t o8;
            o8[0] = (_Float16)((float)x8[0] * iv * s0.x);
            o8[1] = (_Float16)((float)x8[1] * iv * s0.y);
            o8[2] = (_Float16)((float)x8[2] * iv * s0.z);
            o8[3] = (_Float16)((float)x8[3] * iv * s0.w);
            o8[4] = (_Float16)((float)x8[4] * iv * s1.x);
            o8[5] = (_Float16)((float)x8[5] * iv * s1.y);
            o8[6] = (_Float16)((float)x8[6] * iv * s1.z);
            o8[7] = (_Float16)((float)x8[7] * iv * s1.w);
            *(half8_t*)(sh.f.At + rw * XNS + c8) = o8;
        }
        __syncthreads();
        int n0 = wave * 16;
        float4_t acc[2];
        acc[0] = (float4_t){0.f, 0.f, 0.f, 0.f};
        acc[1] = (float4_t){0.f, 0.f, 0.f, 0.f};
        #pragma unroll
        for (int kk = 0; kk < 4; kk++) {
            half8_t a0 = *(const half8_t*)(sh.f.At + r * XNS + kk * 32 + aoff);
            half8_t a1 = *(const half8_t*)(sh.f.At + (16 + r) * XNS + kk * 32 + aoff);
            half8_t wf = *(const half8_t*)(W7 + (wave * 8 + kk * 2 + bsel) * 256 + boff);
            acc[0] = MFMA32(a0, wf, acc[0], 0, 0, 0);
            acc[1] = MFMA32(a1, wf, acc[1], 0, 0, 0);
        }
        int n = n0 + r;
        float bv = lin_b[n];
        #pragma unroll
        for (int rt = 0; rt < 2; rt++) {
            #pragma unroll
            for (int reg = 0; reg < 4; reg++) {
                int row = row0 + rt * 16 + 4 * c + reg;
                float v = fmaxf(acc[rt][reg] + bv, 0.f) + (float)xresh[(size_t)row * 128 + n];
                ffoh[(size_t)row * 128 + n] = (_Float16)v;
            }
        }
    }
    grid_bar(cnt, gen);

    // ================= PHASE F: logits + log_softmax + per-block NLL =================
    if (bid < 128) {
        const _Float16* Wo16 = Wh + 131072;
        int rowb = bid * 128;
        #pragma unroll
        for (int it = 0; it < 4; it++) {
            int idx2 = tid + it * 512;
            int rw = idx2 >> 4, c8 = (idx2 & 15) * 8;
            *(half8_t*)(sh.f.At + rw * XNS + c8) = *(const half8_t*)(ffoh + (size_t)(rowb + rw) * 128 + c8);
        }
        __syncthreads();
        int row0 = rowb + wave * 16;
        half8_t af[4];
        #pragma unroll
        for (int kk = 0; kk < 4; kk++)
            af[kk] = *(const half8_t*)(sh.f.At + (wave * 16 + r) * XNS + kk * 32 + aoff);
        float4_t acc[2];
        acc[0] = (float4_t){0.f, 0.f, 0.f, 0.f};
        acc[1] = (float4_t){0.f, 0.f, 0.f, 0.f};
        #pragma unroll
        for (int kk = 0; kk < 4; kk++) {
            #pragma unroll
            for (int t = 0; t < 2; t++) {
                half8_t wf = *(const half8_t*)(Wo16 + (t * 8 + kk * 2 + bsel) * 256 + boff);
                acc[t] = MFMA32(af[kk], wf, acc[t], 0, 0, 0);
            }
        }
        float b0 = out_b[r], b1 = out_b[r + 16];
        float nll_s = 0.f;
        #pragma unroll
        for (int reg = 0; reg < 4; reg++) {
            int row = row0 + 4 * c + reg;
            float l0 = acc[0][reg] + b0;
            float l1 = acc[1][reg] + b1;
            logits[(size_t)row * 32 + r] = l0;
            logits[(size_t)row * 32 + 16 + r] = l1;
            float mx = fmaxf(l0, l1);
            #pragma unroll
            for (int off = 8; off; off >>= 1) mx = fmaxf(mx, __shfl_xor(mx, off));
            float se = __expf(l0 - mx) + __expf(l1 - mx);
            #pragma unroll
            for (int off = 8; off; off >>= 1) se += __shfl_xor(se, off);
            int tgt = targets[row];
            float sel = (tgt & 16) ? l1 : l0;
            float tval = __shfl(sel, (lane & 48) | (tgt & 15));
            nll_s += logf(se) + mx - tval;
        }
        nll_s += __shfl_xor(nll_s, 16);
        nll_s += __shfl_xor(nll_s, 32);
        if (lane == 0) sh.f.wn[wave] = nll_s;
        __syncthreads();
        if (tid == 0)
            nllPart[bid] = ((sh.f.wn[0] + sh.f.wn[1]) + (sh.f.wn[2] + sh.f.wn[3])) +
                           ((sh.f.wn[4] + sh.f.wn[5]) + (sh.f.wn[6] + sh.f.wn[7]));
    }
    grid_bar(cnt, gen);

    // ================= final loss reduce (block 0, plain store) =================
    if (bid == 0) {
        float v = (tid < 128) ? nllPart[tid] : 0.f;
        #pragma unroll
        for (int off = 32; off; off >>= 1) v += __shfl_xor(v, off);
        __syncthreads();
        if (lane == 0) sh.a.wsum[wave] = v;
        __syncthreads();
        if (tid == 0)
            lossOut[0] = (((sh.a.wsum[0] + sh.a.wsum[1]) + (sh.a.wsum[2] + sh.a.wsum[3])) +
                          ((sh.a.wsum[4] + sh.a.wsum[5]) + (sh.a.wsum[6] + sh.a.wsum[7]))) * (1.0f / (float)BM);
    }
}

extern "C" void kernel_launch(void* const* d_in, const int* in_sizes, int n_in,
                              void* d_out, int out_size, void* d_ws, size_t ws_size,
                              hipStream_t stream) {
    const int*   idx       = (const int*)d_in[0];
    const int*   targets   = (const int*)d_in[1];
    const float* emb       = (const float*)d_in[2];
    const float* rms_scale = (const float*)d_in[3];
    const float* Wq        = (const float*)d_in[4];
    const float* Wk        = (const float*)d_in[5];
    const float* Wv        = (const float*)d_in[6];
    const float* in_w      = (const float*)d_in[7];
    const float* in_b      = (const float*)d_in[8];
    const float* out_pw    = (const float*)d_in[9];
    const float* out_pb    = (const float*)d_in[10];
    const float* lin_w     = (const float*)d_in[11];
    const float* lin_b     = (const float*)d_in[12];
    const float* out_w     = (const float*)d_in[13];
    const float* out_b     = (const float*)d_in[14];
    char* ws  = (char*)d_ws;
    float* out = (float*)d_out;
    unsigned* bar = (unsigned*)(ws + 40 * 1024 * 1024);

    init_kernel<<<1, 64, 0, stream>>>(bar);
    mega_kernel<<<NBLK, 512, 0, stream>>>(idx, targets, emb, rms_scale,
                                          Wq, Wk, Wv, in_w, in_b,
                                          out_pw, out_pb, lin_w, lin_b,
                                          out_w, out_b, ws, out);
}

// Round 6
// 150.114 us; speedup vs baseline: 2.7270x; 2.7270x over previous
//
#include <hip/hip_runtime.h>
#include <hip/hip_bf16.h>
#include <math.h>

#define Vv   32
#define Dd   128
#define Hh   8
#define Bb   8
#define Mm   2048
#define BM   (Bb*Mm)        // 16384
#define NEL  (BM*Dd)        // 2097152
#define XNS  140            // LDS stride (halves) for 128-col tiles, bank-padded
#define QKS  396            // LDS stride (halves) for 384-col qkv tile, bank-padded

typedef _Float16 half4_t __attribute__((ext_vector_type(4)));
typedef _Float16 half8_t __attribute__((ext_vector_type(8)));
typedef __fp16   fp16x2  __attribute__((ext_vector_type(2)));
typedef float    float4_t __attribute__((ext_vector_type(4)));
#define MFMA16 __builtin_amdgcn_mfma_f32_16x16x16f16
#define MFMA32 __builtin_amdgcn_mfma_f32_16x16x32_f16

#if __has_builtin(__builtin_amdgcn_exp2f)
__device__ __forceinline__ float fexp2(float x) { return __builtin_amdgcn_exp2f(x); }
#else
__device__ __forceinline__ float fexp2(float x) { return __expf(x * 0.6931471805599453f); }
#endif

// ---------------- front: [blocks 0..1039] weights->blocked f16 + RoPE tables;
//                  [blocks 1040..3087] embedding ssq partials (no x materialization) ----------------
__global__ __launch_bounds__(256) void front_kernel(const float* __restrict__ Wq,
                                                    const float* __restrict__ Wk,
                                                    const float* __restrict__ Wv,
                                                    const float* __restrict__ in_w,
                                                    const float* __restrict__ out_pw,
                                                    const float* __restrict__ lin_w,
                                                    const float* __restrict__ out_w,
                                                    _Float16* __restrict__ Wh,
                                                    float* __restrict__ cosT,
                                                    float* __restrict__ sinT,
                                                    const int* __restrict__ idx,
                                                    const float* __restrict__ emb,
                                                    float* __restrict__ partials,
                                                    float* __restrict__ lossOut) {
    __shared__ float wsum[4];
    if (blockIdx.x < 1040) {
        if (blockIdx.x == 0 && threadIdx.x == 0) lossOut[0] = 0.f;   // zero loss accumulator
        int gid = blockIdx.x * 256 + threadIdx.x;       // 266240 slots
        if (gid < 135168) {
            const float* src;
            int i;
            if (gid < 131072) {
                int seg = gid >> 14; i = gid & 16383;
                src = seg == 0 ? Wq : seg == 1 ? Wk : seg == 2 ? Wv :
                      seg < 6 ? in_w + (size_t)(seg - 3) * 16384 :
                      seg == 6 ? out_pw : lin_w;
            } else { src = out_w; i = gid - 131072; }   // out_w: 32x128 -> 16 tiles
            int tile = i >> 8, within = i & 255;
            int nt = tile >> 3, kk = tile & 7;
            int r = within >> 4, cc = within & 15;
            Wh[gid] = (_Float16)src[(nt * 16 + r) * 128 + kk * 16 + cc];
        } else {
            int rid = gid - 135168;                     // Mm*64 = 131072
            int i = rid & 63, m = rid >> 6;
            float ex = -2.0f * ((float)i - 1.0f) / 128.0f;
            float basef = expf(ex * 9.210340371976184f);
            float ang = (float)m * basef;
            cosT[rid] = cosf(ang);
            sinT[rid] = sinf(ang);
        }
    } else {
        int blk = blockIdx.x - 1040;                    // 0..2047
        int gid = blk * 256 + threadIdx.x;              // NEL/4
        int token = gid >> 5, t4 = gid & 31;
        float4 x = *(const float4*)(emb + (size_t)idx[token] * 128 + t4 * 4);
        float v = x.x * x.x + x.y * x.y + x.z * x.z + x.w * x.w;
        #pragma unroll
        for (int off = 32; off; off >>= 1) v += __shfl_xor(v, off);
        int lane = threadIdx.x & 63, wave = threadIdx.x >> 6;
        if (lane == 0) wsum[wave] = v;
        __syncthreads();
        if (threadIdx.x == 0) partials[blk] = wsum[0] + wsum[1] + wsum[2] + wsum[3];
    }
}

// ---------------- FUSED: ssq-reduce + gather(emb)+normscale + QKV proj + RoPE + in_proj ----------------
// 8 waves / 512 threads: each wave owns 48 of the 384 output cols (3 16-col tiles).
__global__ __launch_bounds__(512, 4) void gemm_qkvproj_kernel(const int* __restrict__ idx,
                                                              const float* __restrict__ emb,
                                                              const float* __restrict__ scale,
                                                              const float* __restrict__ part1,
                                                              const _Float16* __restrict__ Whqkv,
                                                              const _Float16* __restrict__ Whin,
                                                              const float* __restrict__ in_b,
                                                              const float* __restrict__ cosT,
                                                              const float* __restrict__ sinT,
                                                              _Float16* __restrict__ xnh,
                                                              _Float16* __restrict__ Qp,
                                                              _Float16* __restrict__ Kp,
                                                              _Float16* __restrict__ Vp) {
    __shared__ _Float16 xn[32 * XNS];
    __shared__ _Float16 qkv[32 * QKS];
    __shared__ float wsum0[8];
    int tid = threadIdx.x;
    int row0 = blockIdx.x * 32;
    {
        float v = (tid < 256) ? part1[(row0 >> 11) * 256 + tid] : 0.f;
        #pragma unroll
        for (int off = 32; off; off >>= 1) v += __shfl_xor(v, off);
        if ((tid & 63) == 0) wsum0[tid >> 6] = v;
    }
    __syncthreads();
    float iv = 512.0f / sqrtf(((wsum0[0] + wsum0[1]) + (wsum0[2] + wsum0[3])) +
                              ((wsum0[4] + wsum0[5]) + (wsum0[6] + wsum0[7])));
    {
        int rw = tid >> 4, c8 = (tid & 15) * 8;
        int m = (row0 + rw) & (Mm - 1);
        const float* ep = emb + (size_t)idx[row0 + rw] * 128 + c8;   // emb is 16KB: L1-hot
        float4 xa = *(const float4*)ep;
        float4 xb = *(const float4*)(ep + 4);
        const float* sp = scale + (size_t)m * 128 + c8;
        float4 s0 = *(const float4*)sp;
        float4 s1 = *(const float4*)(sp + 4);
        half8_t o8;
        o8[0] = (_Float16)(xa.x * iv * s0.x);
        o8[1] = (_Float16)(xa.y * iv * s0.y);
        o8[2] = (_Float16)(xa.z * iv * s0.z);
        o8[3] = (_Float16)(xa.w * iv * s0.w);
        o8[4] = (_Float16)(xb.x * iv * s1.x);
        o8[5] = (_Float16)(xb.y * iv * s1.y);
        o8[6] = (_Float16)(xb.z * iv * s1.z);
        o8[7] = (_Float16)(xb.w * iv * s1.w);
        *(half8_t*)(xn + rw * XNS + c8) = o8;
        *(half8_t*)(xnh + (size_t)(row0 + rw) * 128 + c8) = o8;
    }
    __syncthreads();
    int wave = tid >> 6, lane = tid & 63;
    int r = lane & 15, c = lane >> 4;
    int nb = wave * 48;
    // K=32 fragment offsets: lane holds k = c*8 + j (j=0..7) within each 32-k block.
    int aoff = c * 8;                    // A: contiguous 8 halves
    int boff = r * 16 + (c & 1) * 8;     // B: within 16x16 tile kk2*2+(c>>1)
    int bsel = c >> 1;
    {
        float4_t acc[2][3];
        #pragma unroll
        for (int rt = 0; rt < 2; rt++)
            #pragma unroll
            for (int t = 0; t < 3; t++) acc[rt][t] = (float4_t){0.f, 0.f, 0.f, 0.f};
        #pragma unroll
        for (int kk = 0; kk < 4; kk++) {
            half8_t a0 = *(const half8_t*)(xn + r * XNS + kk * 32 + aoff);
            half8_t a1 = *(const half8_t*)(xn + (16 + r) * XNS + kk * 32 + aoff);
            half8_t wf[3];
            #pragma unroll
            for (int t = 0; t < 3; t++)
                wf[t] = *(const half8_t*)(Whqkv + ((wave * 3 + t) * 8 + kk * 2 + bsel) * 256 + boff);
            #pragma unroll
            for (int t = 0; t < 3; t++) {
                acc[0][t] = MFMA32(a0, wf[t], acc[0][t], 0, 0, 0);
                acc[1][t] = MFMA32(a1, wf[t], acc[1][t], 0, 0, 0);
            }
        }
        #pragma unroll
        for (int rt = 0; rt < 2; rt++) {
            #pragma unroll
            for (int t = 0; t < 3; t++) {
                int n = nb + t * 16 + r;
                int ci = (n & 127) >> 1;
                #pragma unroll
                for (int reg = 0; reg < 4; reg++) {
                    int m2 = (row0 + rt * 16 + 4 * c + reg) & (Mm - 1);
                    float v = acc[rt][t][reg];
                    float vp = __shfl_xor(v, 1);     // pair column n^1 lives in lane^1
                    float cs = cosT[m2 * 64 + ci], sn = sinT[m2 * 64 + ci];
                    v = (n & 1) ? (-vp * sn + v * cs) : (v * cs + vp * sn);
                    qkv[(rt * 16 + 4 * c + reg) * QKS + n] = (_Float16)v;
                }
            }
        }
    }
    __syncthreads();
    {
        int seg_lo = nb >> 7;
        int seg_hi = (nb + 32) >> 7;
        float4_t acc[2][3];
        #pragma unroll
        for (int rt = 0; rt < 2; rt++)
            #pragma unroll
            for (int t = 0; t < 3; t++) acc[rt][t] = (float4_t){0.f, 0.f, 0.f, 0.f};
        #pragma unroll
        for (int kk = 0; kk < 4; kk++) {
            half8_t al0 = *(const half8_t*)(qkv + r * QKS + seg_lo * 128 + kk * 32 + aoff);
            half8_t al1 = *(const half8_t*)(qkv + (16 + r) * QKS + seg_lo * 128 + kk * 32 + aoff);
            half8_t ah0 = *(const half8_t*)(qkv + r * QKS + seg_hi * 128 + kk * 32 + aoff);
            half8_t ah1 = *(const half8_t*)(qkv + (16 + r) * QKS + seg_hi * 128 + kk * 32 + aoff);
            #pragma unroll
            for (int t = 0; t < 3; t++) {
                int colg = nb + t * 16;
                int seg = colg >> 7;
                int ntl = (colg & 127) >> 4;
                half8_t wf = *(const half8_t*)(Whin + ((seg * 8 + ntl) * 8 + kk * 2 + bsel) * 256 + boff);
                bool lo = (seg == seg_lo);
                acc[0][t] = MFMA32(lo ? al0 : ah0, wf, acc[0][t], 0, 0, 0);
                acc[1][t] = MFMA32(lo ? al1 : ah1, wf, acc[1][t], 0, 0, 0);
            }
        }
        int bb = row0 >> 11;
        #pragma unroll
        for (int rt = 0; rt < 2; rt++) {
            int t16 = ((row0 + rt * 16) & 2047) >> 4;
            #pragma unroll
            for (int t = 0; t < 3; t++) {
                int colg = nb + t * 16;
                int seg = colg >> 7;
                int h = (colg & 127) >> 4;
                size_t tb = ((size_t)(bb * 8 + h) * 128 + t16) * 256;
                float bv = in_b[colg + r];
                _Float16* dst = seg == 0 ? Qp : seg == 1 ? Kp : Vp;
                #pragma unroll
                for (int reg = 0; reg < 4; reg++) {
                    float v = acc[rt][t][reg] + bv;
                    int key = 4 * c + reg;
                    if (seg < 2) dst[tb + key * 16 + r] = (_Float16)v;   // [token][d=r]
                    else         dst[tb + r * 16 + key] = (_Float16)v;   // [d=r][token]
                }
            }
        }
    }
}

// ---------------- out_proj: Oh f16 @ W^T + bias + resid(xnh) -> xresh f16, ssq partials ----------------
// 8 waves / 512 threads: wave owns 16 of 128 output cols.
__global__ __launch_bounds__(512, 4) void gemm_ep1_kernel(const _Float16* __restrict__ Oh,
                                                          const _Float16* __restrict__ W6,
                                                          const float* __restrict__ bias,
                                                          const _Float16* __restrict__ xnh,
                                                          _Float16* __restrict__ xresh,
                                                          float* __restrict__ partials) {
    __shared__ _Float16 At[32 * XNS];
    int tid = threadIdx.x;
    int row0 = blockIdx.x * 32;
    {
        int rw = tid >> 4, c8 = (tid & 15) * 8;
        *(half8_t*)(At + rw * XNS + c8) = *(const half8_t*)(Oh + (size_t)(row0 + rw) * 128 + c8);
    }
    __syncthreads();
    int wave = tid >> 6, lane = tid & 63;
    int r = lane & 15, c = lane >> 4;
    int aoff = c * 8;
    int boff = r * 16 + (c & 1) * 8;
    int bsel = c >> 1;
    int n0 = wave * 16;
    float4_t acc[2];
    acc[0] = (float4_t){0.f, 0.f, 0.f, 0.f};
    acc[1] = (float4_t){0.f, 0.f, 0.f, 0.f};
    #pragma unroll
    for (int kk = 0; kk < 4; kk++) {
        half8_t a0 = *(const half8_t*)(At + r * XNS + kk * 32 + aoff);
        half8_t a1 = *(const half8_t*)(At + (16 + r) * XNS + kk * 32 + aoff);
        half8_t wf = *(const half8_t*)(W6 + (wave * 8 + kk * 2 + bsel) * 256 + boff);
        acc[0] = MFMA32(a0, wf, acc[0], 0, 0, 0);
        acc[1] = MFMA32(a1, wf, acc[1], 0, 0, 0);
    }
    float lssq = 0.f;
    int n = n0 + r;
    float bv = bias[n];
    #pragma unroll
    for (int rt = 0; rt < 2; rt++) {
        #pragma unroll
        for (int reg = 0; reg < 4; reg++) {
            int row = row0 + rt * 16 + 4 * c + reg;
            float v = acc[rt][reg] + bv + (float)xnh[(size_t)row * 128 + n];
            lssq += v * v;
            xresh[(size_t)row * 128 + n] = (_Float16)v;
        }
    }
    #pragma unroll
    for (int off = 32; off; off >>= 1) lssq += __shfl_xor(lssq, off);
    __shared__ float wsum[8];
    if (lane == 0) wsum[wave] = lssq;
    __syncthreads();
    if (tid == 0) partials[blockIdx.x] = ((wsum[0] + wsum[1]) + (wsum[2] + wsum[3])) +
                                        ((wsum[4] + wsum[5]) + (wsum[6] + wsum[7]));
}

// ---------------- FUSED FFN+LOGITS: rmsnorm + GEMM + relu + resid -> LDS -> logits + NLL ----------------
// ffoh never hits global: consumed in-block by the logits GEMM.
__global__ __launch_bounds__(512, 4) void gemm_ep2_logits_kernel(const _Float16* __restrict__ xresh,
                                                                 const float* __restrict__ scale,
                                                                 const float* __restrict__ part2,
                                                                 const _Float16* __restrict__ W7,
                                                                 const float* __restrict__ bias,
                                                                 const _Float16* __restrict__ Wo16,
                                                                 const float* __restrict__ bo,
                                                                 const int* __restrict__ targets,
                                                                 float* __restrict__ logits,
                                                                 float* __restrict__ lossOut) {
    __shared__ _Float16 At[32 * XNS];
    __shared__ _Float16 Ao[32 * XNS];
    __shared__ float wn[2];
    int tid = threadIdx.x;
    int row0 = blockIdx.x * 32;
    float pv = part2[(row0 >> 11) * 64 + (tid & 63)];
    #pragma unroll
    for (int off = 32; off; off >>= 1) pv += __shfl_xor(pv, off);
    float iv = 512.0f / sqrtf(pv);
    {
        int rw = tid >> 4, c8 = (tid & 15) * 8;
        int m = (row0 + rw) & (Mm - 1);
        half8_t x8 = *(const half8_t*)(xresh + (size_t)(row0 + rw) * 128 + c8);
        const float* sp = scale + (size_t)m * 128 + c8;
        float4 s0 = *(const float4*)sp;
        float4 s1 = *(const float4*)(sp + 4);
        half8_t o8;
        o8[0] = (_Float16)((float)x8[0] * iv * s0.x);
        o8[1] = (_Float16)((float)x8[1] * iv * s0.y);
        o8[2] = (_Float16)((float)x8[2] * iv * s0.z);
        o8[3] = (_Float16)((float)x8[3] * iv * s0.w);
        o8[4] = (_Float16)((float)x8[4] * iv * s1.x);
        o8[5] = (_Float16)((float)x8[5] * iv * s1.y);
        o8[6] = (_Float16)((float)x8[6] * iv * s1.z);
        o8[7] = (_Float16)((float)x8[7] * iv * s1.w);
        *(half8_t*)(At + rw * XNS + c8) = o8;
    }
    __syncthreads();
    int wave = tid >> 6, lane = tid & 63;
    int r = lane & 15, c = lane >> 4;
    int aoff = c * 8;
    int boff = r * 16 + (c & 1) * 8;
    int bsel = c >> 1;
    int n0 = wave * 16;
    float4_t acc[2];
    acc[0] = (float4_t){0.f, 0.f, 0.f, 0.f};
    acc[1] = (float4_t){0.f, 0.f, 0.f, 0.f};
    #pragma unroll
    for (int kk = 0; kk < 4; kk++) {
        half8_t a0 = *(const half8_t*)(At + r * XNS + kk * 32 + aoff);
        half8_t a1 = *(const half8_t*)(At + (16 + r) * XNS + kk * 32 + aoff);
        half8_t wf = *(const half8_t*)(W7 + (wave * 8 + kk * 2 + bsel) * 256 + boff);
        acc[0] = MFMA32(a0, wf, acc[0], 0, 0, 0);
        acc[1] = MFMA32(a1, wf, acc[1], 0, 0, 0);
    }
    int n = n0 + r;
    float bv = bias[n];
    #pragma unroll
    for (int rt = 0; rt < 2; rt++) {
        #pragma unroll
        for (int reg = 0; reg < 4; reg++) {
            int row = row0 + rt * 16 + 4 * c + reg;
            int rowl = rt * 16 + 4 * c + reg;
            float v = fmaxf(acc[rt][reg] + bv, 0.f) + (float)xresh[(size_t)row * 128 + n];
            Ao[rowl * XNS + n] = (_Float16)v;        // ffn output stays in LDS
        }
    }
    __syncthreads();
    // ---- logits + log_softmax + NLL on the 32 rows (waves 0,1: 16 rows each) ----
    if (wave < 2) {
        int rloc = wave * 16;
        half8_t af[4];
        #pragma unroll
        for (int kk = 0; kk < 4; kk++)
            af[kk] = *(const half8_t*)(Ao + (rloc + r) * XNS + kk * 32 + aoff);
        float4_t lacc[2];
        lacc[0] = (float4_t){0.f, 0.f, 0.f, 0.f};
        lacc[1] = (float4_t){0.f, 0.f, 0.f, 0.f};
        #pragma unroll
        for (int kk = 0; kk < 4; kk++) {
            #pragma unroll
            for (int t = 0; t < 2; t++) {
                half8_t wf = *(const half8_t*)(Wo16 + (t * 8 + kk * 2 + bsel) * 256 + boff);
                lacc[t] = MFMA32(af[kk], wf, lacc[t], 0, 0, 0);
            }
        }
        float b0 = bo[r], b1 = bo[r + 16];
        float nll_s = 0.f;
        #pragma unroll
        for (int reg = 0; reg < 4; reg++) {
            int row = row0 + rloc + 4 * c + reg;
            float l0 = lacc[0][reg] + b0;
            float l1 = lacc[1][reg] + b1;
            logits[(size_t)row * 32 + r] = l0;
            logits[(size_t)row * 32 + 16 + r] = l1;
            float mx = fmaxf(l0, l1);
            #pragma unroll
            for (int off = 8; off; off >>= 1) mx = fmaxf(mx, __shfl_xor(mx, off));
            float se = __expf(l0 - mx) + __expf(l1 - mx);
            #pragma unroll
            for (int off = 8; off; off >>= 1) se += __shfl_xor(se, off);
            int tgt = targets[row];
            float sel = (tgt & 16) ? l1 : l0;
            float tval = __shfl(sel, (lane & 48) | (tgt & 15));
            nll_s += logf(se) + mx - tval;           // identical across the 16 r-lanes of this c-group
        }
        nll_s += __shfl_xor(nll_s, 16);
        nll_s += __shfl_xor(nll_s, 32);
        if (lane == 0) wn[wave] = nll_s;
    }
    __syncthreads();
    if (tid == 0) atomicAdd(lossOut, (wn[0] + wn[1]) * (1.0f / (float)BM));
}

// ---------------- attention helpers (plain-add denominator) ----------------
__device__ __forceinline__ half4_t attn_exps(float4_t st, float& ls) {
    float p0 = fexp2(st[0]), p1 = fexp2(st[1]);
    float p2 = fexp2(st[2]), p3 = fexp2(st[3]);
    ls += (p0 + p1) + (p2 + p3);
    fp16x2 lo = __builtin_amdgcn_cvt_pkrtz(p0, p1);
    fp16x2 hi = __builtin_amdgcn_cvt_pkrtz(p2, p3);
    half4_t pf;
    pf[0] = (_Float16)lo[0]; pf[1] = (_Float16)lo[1];
    pf[2] = (_Float16)hi[0]; pf[3] = (_Float16)hi[1];
    return pf;
}
__device__ __forceinline__ half4_t attn_exps_masked(float4_t st, float& ls, int r, int c) {
    float p0 = (4 * c + 0 <= r) ? fexp2(st[0]) : 0.f;
    float p1 = (4 * c + 1 <= r) ? fexp2(st[1]) : 0.f;
    float p2 = (4 * c + 2 <= r) ? fexp2(st[2]) : 0.f;
    float p3 = (4 * c + 3 <= r) ? fexp2(st[3]) : 0.f;
    ls += (p0 + p1) + (p2 + p3);
    fp16x2 lo = __builtin_amdgcn_cvt_pkrtz(p0, p1);
    fp16x2 hi = __builtin_amdgcn_cvt_pkrtz(p2, p3);
    half4_t pf;
    pf[0] = (_Float16)lo[0]; pf[1] = (_Float16)lo[1];
    pf[2] = (_Float16)hi[0]; pf[3] = (_Float16)hi[1];
    return pf;
}

// ---------------- MFMA flash attention: paired q-tiles + split-K (2 waves/pair) ----------------
__global__ __launch_bounds__(256) void attn_kernel(const _Float16* __restrict__ Qp,
                                                   const _Float16* __restrict__ Kp,
                                                   const _Float16* __restrict__ Vp,
                                                   _Float16* __restrict__ Oh) {
    __shared__ float mrg[2][10][64];
    int wave = threadIdx.x >> 6, lane = threadIdx.x & 63;
    int pair = blockIdx.x * 2 + (wave >> 1);         // 0..4095
    int split = wave & 1;
    int qa = pair & 63, bh = pair >> 6, qb = 127 - qa;
    int r = lane & 15, c = lane >> 4;
    int lofs = r * 16 + 4 * c;
    const _Float16* Kb = Kp + (size_t)bh * 32768 + lofs;
    const _Float16* Vb = Vp + (size_t)bh * 32768 + lofs;
    const _Float16* Qb = Qp + (size_t)bh * 32768 + lofs;
    half4_t qfa = *(const half4_t*)(Qb + qa * 256);
    half4_t qfb = *(const half4_t*)(Qb + qb * 256);
    const _Float16 qscale = (_Float16)0.36067376f;   // 0.25 * log2(e)
    qfa *= qscale;
    qfb *= qscale;
    float4_t zero = {0.f, 0.f, 0.f, 0.f};
    float4_t oa = zero, ob = zero;
    float lsa = 0.f, lsb = 0.f;

    for (int kt = split; kt < qa; kt += 2) {
        half4_t k0 = *(const half4_t*)(Kb + (size_t)kt * 256);
        half4_t v0 = *(const half4_t*)(Vb + (size_t)kt * 256);
        float4_t sa = MFMA16(k0, qfa, zero, 0, 0, 0);
        float4_t sb = MFMA16(k0, qfb, zero, 0, 0, 0);
        half4_t pa = attn_exps(sa, lsa);
        half4_t pb = attn_exps(sb, lsb);
        oa = MFMA16(pa, v0, oa, 0, 0, 0);
        ob = MFMA16(pb, v0, ob, 0, 0, 0);
    }
    if ((qa & 1) == split) {                         // tile qa: masked for a, full for b
        half4_t k0 = *(const half4_t*)(Kb + (size_t)qa * 256);
        half4_t v0 = *(const half4_t*)(Vb + (size_t)qa * 256);
        float4_t sa = MFMA16(k0, qfa, zero, 0, 0, 0);
        float4_t sb = MFMA16(k0, qfb, zero, 0, 0, 0);
        half4_t pa = attn_exps_masked(sa, lsa, r, c);
        half4_t pb = attn_exps(sb, lsb);
        oa = MFMA16(pa, v0, oa, 0, 0, 0);
        ob = MFMA16(pb, v0, ob, 0, 0, 0);
    }
    {
        int s = qa + 1;
        if ((s & 1) != split) s++;
        for (int kt = s; kt < qb; kt += 2) {
            half4_t k0 = *(const half4_t*)(Kb + (size_t)kt * 256);
            half4_t v0 = *(const half4_t*)(Vb + (size_t)kt * 256);
            float4_t sb = MFMA16(k0, qfb, zero, 0, 0, 0);
            half4_t pb = attn_exps(sb, lsb);
            ob = MFMA16(pb, v0, ob, 0, 0, 0);
        }
    }
    if ((qb & 1) == split) {                         // tile qb: masked for b
        half4_t k0 = *(const half4_t*)(Kb + (size_t)qb * 256);
        half4_t v0 = *(const half4_t*)(Vb + (size_t)qb * 256);
        float4_t sb = MFMA16(k0, qfb, zero, 0, 0, 0);
        half4_t pb = attn_exps_masked(sb, lsb, r, c);
        ob = MFMA16(pb, v0, ob, 0, 0, 0);
    }
    int pib = wave >> 1;
    if (split == 1) {
        #pragma unroll
        for (int i = 0; i < 4; i++) {
            mrg[pib][i][lane] = oa[i];
            mrg[pib][4 + i][lane] = ob[i];
        }
        mrg[pib][8][lane] = lsa;
        mrg[pib][9][lane] = lsb;
    }
    __syncthreads();
    if (split == 0) {
        #pragma unroll
        for (int i = 0; i < 4; i++) {
            oa[i] += mrg[pib][i][lane];
            ob[i] += mrg[pib][4 + i][lane];
        }
        lsa += mrg[pib][8][lane];
        lsb += mrg[pib][9][lane];
        lsa += __shfl_xor(lsa, 16); lsa += __shfl_xor(lsa, 32);
        lsb += __shfl_xor(lsb, 16); lsb += __shfl_xor(lsb, 32);
        int b = bh >> 3, h = bh & 7;
        #pragma unroll
        for (int reg = 0; reg < 4; reg++) {
            float la = __shfl(lsa, 4 * c + reg);
            float lb = __shfl(lsb, 4 * c + reg);
            Oh[(size_t)(b * Mm + qa * 16 + 4 * c + reg) * 128 + h * 16 + r] = (_Float16)(oa[reg] / la);
            Oh[(size_t)(b * Mm + qb * 16 + 4 * c + reg) * 128 + h * 16 + r] = (_Float16)(ob[reg] / lb);
        }
    }
}

extern "C" void kernel_launch(void* const* d_in, const int* in_sizes, int n_in,
                              void* d_out, int out_size, void* d_ws, size_t ws_size,
                              hipStream_t stream) {
    const int*   idx       = (const int*)d_in[0];
    const int*   targets   = (const int*)d_in[1];
    const float* emb       = (const float*)d_in[2];
    const float* rms_scale = (const float*)d_in[3];
    const float* Wq        = (const float*)d_in[4];
    const float* Wk        = (const float*)d_in[5];
    const float* Wv        = (const float*)d_in[6];
    const float* in_w      = (const float*)d_in[7];
    const float* in_b      = (const float*)d_in[8];
    const float* out_pw    = (const float*)d_in[9];
    const float* out_pb    = (const float*)d_in[10];
    const float* lin_w     = (const float*)d_in[11];
    const float* lin_b     = (const float*)d_in[12];
    const float* out_w     = (const float*)d_in[13];
    const float* out_b     = (const float*)d_in[14];
    float* out = (float*)d_out;
    float* lossOut = out + (size_t)BM * Vv;

    char* base = (char*)d_ws;
    const size_t MB = 1024 * 1024;
    _Float16* xnh   = (_Float16*)(base + 4 * MB);      // 4..8MB   normed x (resid for ep1)
    _Float16* Oh    = (_Float16*)(base + 8 * MB);      // 8..12MB  attn out (f16)
    _Float16* xresh = (_Float16*)(base + 12 * MB);     // 12..16MB residual-2 (f16)
    _Float16* Qp    = (_Float16*)(base + 20 * MB);     // 20..24MB
    _Float16* Kp    = (_Float16*)(base + 24 * MB);     // 24..28MB
    _Float16* Vp    = (_Float16*)(base + 28 * MB);     // 28..32MB
    float*    cosT  = (float*)(base + 32 * MB);        // 512KB
    float*    sinT  = cosT + Mm * 64;                  // 512KB
    float*    part1 = sinT + Mm * 64;                  // 2048
    float*    part2 = part1 + 2048;                    // 512
    _Float16* Wh    = (_Float16*)(part2 + 512);        // 135168 halves (8 mats + out_w, blocked)

    front_kernel<<<1040 + 2048, 256, 0, stream>>>(Wq, Wk, Wv, in_w, out_pw, lin_w, out_w,
                                                  Wh, cosT, sinT, idx, emb, part1, lossOut);

    gemm_qkvproj_kernel<<<BM / 32, 512, 0, stream>>>(idx, emb, rms_scale, part1,
                                                     Wh, Wh + 3 * 16384, in_b,
                                                     cosT, sinT, xnh, Qp, Kp, Vp);

    attn_kernel<<<4096 / 2, 256, 0, stream>>>(Qp, Kp, Vp, Oh);

    gemm_ep1_kernel<<<BM / 32, 512, 0, stream>>>(Oh, Wh + 6 * 16384, out_pb, xnh, xresh, part2);

    gemm_ep2_logits_kernel<<<BM / 32, 512, 0, stream>>>(xresh, rms_scale, part2,
                                                        Wh + 7 * 16384, lin_b,
                                                        Wh + 131072, out_b, targets,
                                                        out, lossOut);
}